// Round 10
// baseline (324.360 us; speedup 1.0000x reference)
//
#include <hip/hip_runtime.h>

// MiniCPM-style decode step: L=8 B=4 H=16 HKV=8 D=64 S=2048 HID=1024 FF=2816
#define L_   8
#define B_   4
#define H_   16
#define HKV_ 8
#define D_   64
#define S_   2048
#define HID_ 1024
#define FF_  2816
#define EPS_ 1e-5f
#define MUP_ 0.49497474683058327f   // 1.4/sqrt(8)
#define SCALE_ 0.125f               // 1/sqrt(64)
#define NCH_ 32                     // attention chunks of 64 positions

// d_out is FLOAT32: [h 4096 | k_upd 16384 | v_upd 16384 | pos+1]
#define OUT_H   0
#define OUT_K   4096
#define OUT_V   (4096 + 16384)
#define OUT_POS (4096 + 16384 + 16384)

// ---------------- workspace layout (floats); partials [kc][b][col] ----------------
enum {
  WS_HC  = 0,                        // 4096   live hidden state (atomics target)
  WS_QP  = 4096,                     // 32*4*2048 = 262144
  WS_AM  = WS_QP + 262144,           // 2048   [b][kv][2][32]
  WS_AL  = WS_AM + 2048,             // 2048
  WS_AO  = WS_AL + 2048,             // 4*16*32*64 = 131072
  WS_GP  = WS_AO + 131072,           // 32*4*2816 = 360448
  WS_UP  = WS_GP + 360448,           // 360448
  WS_END = WS_UP + 360448            // ~4.5 MB
};

__device__ __forceinline__ int read_pos_dev(const int* p) {
  int v = p[0];
  if (v >= 0 && v < S_) return v;
  float f = __int_as_float(v);
  if (f >= 0.0f && f <= (float)(S_ - 1)) return (int)(f + 0.5f);
  return 1500;
}

__device__ __forceinline__ float wave_sum(float v) {
  for (int m = 1; m < 64; m <<= 1) v += __shfl_xor(v, m);
  return v;
}
__device__ __forceinline__ float wave_max(float v) {
  for (int m = 1; m < 64; m <<= 1) v = fmaxf(v, __shfl_xor(v, m));
  return v;
}

// shared RMS prologue: read 4x1024 h, per-batch rsqrt(mean sq)
__device__ __forceinline__ void rms_of(const float* hsrc, float* red, float* rs) {
  int t = threadIdx.x;
  float part[4] = {0.f, 0.f, 0.f, 0.f};
  #pragma unroll
  for (int j = 0; j < 4; ++j) {
    int c2 = t + j * 256;
    #pragma unroll
    for (int b = 0; b < 4; ++b) {
      float v = hsrc[b * HID_ + c2];
      part[b] += v * v;
    }
  }
  int w = t >> 6;
  #pragma unroll
  for (int b = 0; b < 4; ++b) {
    float s = wave_sum(part[b]);
    if ((t & 63) == 0) red[w * 4 + b] = s;
  }
  __syncthreads();
  #pragma unroll
  for (int b = 0; b < 4; ++b)
    rs[b] = rsqrtf((red[b] + red[4 + b] + red[8 + b] + red[12 + b]) * (1.0f / HID_) + EPS_);
}

// ================= K1: QKV GEMV (RMS prologue, no combine) =================
// grid 256 = 8 cb x 32 kc (32 rows each)
__global__ void __launch_bounds__(256)
k1_qkv(const float* __restrict__ Wq, const float* __restrict__ Wk,
       const float* __restrict__ Wv, const float* __restrict__ n1,
       const float* __restrict__ x, float* __restrict__ ws, int l) {
  int cb = blockIdx.x & 7, kc = blockIdx.x >> 3;
  int t = threadIdx.x;
  int col = cb * 256 + t;
  const float* W; int wcol, stride;
  if (col < 1024)      { W = Wq + (size_t)l * HID_ * 1024; wcol = col;        stride = 1024; }
  else if (col < 1536) { W = Wk + (size_t)l * HID_ * 512;  wcol = col - 1024; stride = 512;  }
  else                 { W = Wv + (size_t)l * HID_ * 512;  wcol = col - 1536; stride = 512;  }
  const float* wp = W + (size_t)(kc * 32) * stride + wcol;
  float wv[32];
  #pragma unroll
  for (int i = 0; i < 32; ++i) wv[i] = wp[(size_t)i * stride];   // in flight

  const float* hsrc = (l == 0) ? x : (ws + WS_HC);
  __shared__ float red[16];
  __shared__ __align__(16) float xs[4][32];
  float rs[4];
  rms_of(hsrc, red, rs);
  if (l == 0 && blockIdx.x < 4) {        // seed HC = x (blocks 0-3, one batch each)
    for (int j = 0; j < 4; ++j) {
      int c2 = t + j * 256;
      ws[WS_HC + blockIdx.x * HID_ + c2] = x[blockIdx.x * HID_ + c2];
    }
  }
  if (t < 128) {
    int b = t >> 5, i = t & 31;
    int gc = kc * 32 + i;
    xs[b][i] = hsrc[b * HID_ + gc] * rs[b] * n1[l * HID_ + gc];
  }
  __syncthreads();
  float a0 = 0.f, a1 = 0.f, a2 = 0.f, a3 = 0.f;
  #pragma unroll
  for (int i = 0; i < 32; ++i) {
    float w_ = wv[i];
    a0 += w_ * xs[0][i]; a1 += w_ * xs[1][i];
    a2 += w_ * xs[2][i]; a3 += w_ * xs[3][i];
  }
  ws[WS_QP + ((size_t)kc * 4 + 0) * 2048 + col] = a0;
  ws[WS_QP + ((size_t)kc * 4 + 1) * 2048 + col] = a1;
  ws[WS_QP + ((size_t)kc * 4 + 2) * 2048 + col] = a2;
  ws[WS_QP + ((size_t)kc * 4 + 3) * 2048 + col] = a3;
}

// ================= K2: qkv-combine + rope + kv-out + flash chunk (LDS-staged) ==
// grid 1024 = (b,kv) x 32 chunks of 64 positions; chunks beyond pos skip fast
__global__ void __launch_bounds__(256)
k2_attn(const float* __restrict__ kcache, const float* __restrict__ vcache,
        const int* __restrict__ posp, float* __restrict__ ws,
        float* __restrict__ out, int l) {
  int bh = blockIdx.x >> 5, ns = blockIdx.x & 31;
  int b = bh >> 3, kv = bh & 7;
  int t = threadIdx.x;
  int w = t >> 6, lane = t & 63, r = lane >> 4, c = lane & 15;
  int pos = read_pos_dev(posp);
  int s0 = ns * 64;
  if (s0 > pos) {                      // fully-masked chunk: sentinels, no traffic
    if (t == 0) {
      int base = ((b * HKV_ + kv) * 2) * NCH_ + ns;
      ws[WS_AM + base] = -1e30f;       ws[WS_AM + base + NCH_] = -1e30f;
      ws[WS_AL + base] = 0.f;          ws[WS_AL + base + NCH_] = 0.f;
    }
    return;
  }
  __shared__ __align__(16) float Kst[64 * 68];   // padded rows (68) = conflict-free
  __shared__ __align__(16) float Vst[64 * 68];
  __shared__ __align__(16) float qL[2][64];
  __shared__ __align__(16) float knL[64], vnL[64];
  __shared__ float rawL[256], sc0[64], sc1[64], red[8];
  __shared__ __align__(16) float oacc[2][4][64];

  const float* Kb = kcache + (((size_t)l * B_ + b) * HKV_ + kv) * S_ * 64;
  const float* Vb = vcache + (((size_t)l * B_ + b) * HKV_ + kv) * S_ * 64;

  // stage K/V chunk rows (branch-free float4 streams), padded-row layout
  {
    const float4* Ksrc = (const float4*)(Kb + (size_t)s0 * 64);
    const float4* Vsrc = (const float4*)(Vb + (size_t)s0 * 64);
    #pragma unroll
    for (int i = 0; i < 4; ++i) {
      int f4 = t + i * 256;                 // 0..1023
      int row = f4 >> 4, c4 = f4 & 15;
      float4 kk = Ksrc[f4];
      float4 vv = Vsrc[f4];
      *(float4*)&Kst[row * 68 + 4 * c4] = kk;
      *(float4*)&Vst[row * 68 + 4 * c4] = vv;
    }
  }

  // combine qkv partials -> rawL; rope
  int cg;
  if (t < 128)      cg = (kv * 2 + (t >> 6)) * 64 + (t & 63);
  else if (t < 192) cg = 1024 + kv * 64 + (t & 63);
  else              cg = 1536 + kv * 64 + (t & 63);
  float s = 0.f;
  #pragma unroll
  for (int q = 0; q < 32; ++q) s += ws[WS_QP + ((size_t)q * 4 + b) * 2048 + cg];
  rawL[t] = s;
  __syncthreads();
  {
    int dd = t & 63;
    if (t < 192) {
      int idx = dd & 31;
      float inv = expf(-(float)idx * (1.0f / 32.0f) * 9.210340371976184f);
      float ang = (float)pos * inv;
      float sn, cs; __sincosf(ang, &sn, &cs);
      float partner = rawL[t ^ 32];
      float rot = (dd < 32) ? -partner : partner;
      float v = rawL[t] * cs + rot * sn;
      if (t < 128) qL[t >> 6][dd] = v;
      else {
        knL[dd] = v;
        if (ns == 0) out[OUT_K + (((size_t)l * B_ + b) * HKV_ + kv) * 64 + dd] = v;
      }
    } else {
      vnL[dd] = rawL[t];
      if (ns == 0) out[OUT_V + (((size_t)l * B_ + b) * HKV_ + kv) * 64 + dd] = rawL[t];
    }
  }
  __syncthreads();
  // substitute the new-token row if it falls in this chunk
  if (pos >= s0 && pos < s0 + 64) {
    int row = pos - s0;
    if (t < 64)                Kst[row * 68 + t] = knL[t];
    else if (t < 128)          Vst[row * 68 + (t - 64)] = vnL[t - 64];
  }
  __syncthreads();

  float4 q0 = *(float4*)&qL[0][4 * c];
  float4 q1 = *(float4*)&qL[1][4 * c];
  // scores from LDS
  #pragma unroll
  for (int it = 0; it < 4; ++it) {
    int row = it * 16 + w * 4 + r;
    int sp = s0 + row;
    float4 k4 = *(float4*)&Kst[row * 68 + 4 * c];
    float d0 = k4.x * q0.x + k4.y * q0.y + k4.z * q0.z + k4.w * q0.w;
    float d1 = k4.x * q1.x + k4.y * q1.y + k4.z * q1.z + k4.w * q1.w;
    #pragma unroll
    for (int m = 1; m <= 8; m <<= 1) { d0 += __shfl_xor(d0, m); d1 += __shfl_xor(d1, m); }
    if (c == 0) {
      bool valid = (sp <= pos);
      sc0[row] = valid ? d0 * SCALE_ : -1e30f;
      sc1[row] = valid ? d1 * SCALE_ : -1e30f;
    }
  }
  __syncthreads();
  // chunk softmax
  float v0 = (t < 64) ? sc0[t] : -1e30f;
  float v1 = (t < 64) ? sc1[t] : -1e30f;
  float m0 = wave_max(v0), m1 = wave_max(v1);
  if (lane == 0) { red[w] = m0; red[4 + w] = m1; }
  __syncthreads();
  m0 = fmaxf(fmaxf(red[0], red[1]), fmaxf(red[2], red[3]));
  m1 = fmaxf(fmaxf(red[4], red[5]), fmaxf(red[6], red[7]));
  float e0 = (t < 64) ? expf(v0 - m0) : 0.f;
  float e1 = (t < 64) ? expf(v1 - m1) : 0.f;
  __syncthreads();
  if (t < 64) { sc0[t] = e0; sc1[t] = e1; }
  float se0 = wave_sum(e0), se1 = wave_sum(e1);
  if (lane == 0) { red[w] = se0; red[4 + w] = se1; }
  __syncthreads();
  if (t == 0) {
    int base = ((b * HKV_ + kv) * 2) * NCH_ + ns;
    ws[WS_AM + base] = m0;          ws[WS_AM + base + NCH_] = m1;
    ws[WS_AL + base] = red[0] + red[1] + red[2] + red[3];
    ws[WS_AL + base + NCH_] = red[4] + red[5] + red[6] + red[7];
  }
  // PV from LDS
  float4 a0 = make_float4(0.f, 0.f, 0.f, 0.f);
  float4 a1 = make_float4(0.f, 0.f, 0.f, 0.f);
  #pragma unroll
  for (int it = 0; it < 4; ++it) {
    int row = it * 16 + w * 4 + r;
    float4 v4 = *(float4*)&Vst[row * 68 + 4 * c];
    float p0 = sc0[row], p1 = sc1[row];
    a0.x += p0 * v4.x; a0.y += p0 * v4.y; a0.z += p0 * v4.z; a0.w += p0 * v4.w;
    a1.x += p1 * v4.x; a1.y += p1 * v4.y; a1.z += p1 * v4.z; a1.w += p1 * v4.w;
  }
  #pragma unroll
  for (int m = 16; m <= 32; m <<= 1) {
    a0.x += __shfl_xor(a0.x, m); a0.y += __shfl_xor(a0.y, m);
    a0.z += __shfl_xor(a0.z, m); a0.w += __shfl_xor(a0.w, m);
    a1.x += __shfl_xor(a1.x, m); a1.y += __shfl_xor(a1.y, m);
    a1.z += __shfl_xor(a1.z, m); a1.w += __shfl_xor(a1.w, m);
  }
  if (r == 0) {
    *(float4*)&oacc[0][w][4 * c] = a0;
    *(float4*)&oacc[1][w][4 * c] = a1;
  }
  __syncthreads();
  if (t < 64) {
    float r0 = oacc[0][0][t] + oacc[0][1][t] + oacc[0][2][t] + oacc[0][3][t];
    float r1 = oacc[1][0][t] + oacc[1][1][t] + oacc[1][2][t] + oacc[1][3][t];
    int h0 = kv * 2;
    ws[WS_AO + ((size_t)(b * H_ + h0)     * NCH_ + ns) * 64 + t] = r0;
    ws[WS_AO + ((size_t)(b * H_ + h0 + 1) * NCH_ + ns) * 64 + t] = r1;
  }
}

// ================= K3: o-proj GEMV, atomicAdd residual into HC ===============
// grid 256 = 4 cb x 64 kc (16 rows each)
__global__ void __launch_bounds__(256)
k3_oproj(const float* __restrict__ Wo, float* __restrict__ ws, int l) {
  int cb = blockIdx.x & 3, kc = blockIdx.x >> 2;   // kc<64
  int t = threadIdx.x;
  int col = cb * 256 + t;
  const float* wp = Wo + ((size_t)l * HID_ + kc * 16) * HID_ + col;
  float wv[16];
  #pragma unroll
  for (int i = 0; i < 16; ++i) wv[i] = wp[(size_t)i * HID_];    // in flight

  __shared__ __align__(16) float oT[16][4];
  if (t < 64) {
    int jj = t >> 2, bb = t & 3;
    int dim = kc * 16 + jj, h = dim >> 6, d = dim & 63;
    int mb = ((bb * HKV_ + (h >> 1)) * 2 + (h & 1)) * NCH_;
    float mx = -1e30f;
    #pragma unroll
    for (int n = 0; n < NCH_; ++n) mx = fmaxf(mx, ws[WS_AM + mb + n]);
    float ls = 0.f, os = 0.f;
    #pragma unroll
    for (int n = 0; n < NCH_; ++n) {
      float wg = expf(ws[WS_AM + mb + n] - mx);
      ls += wg * ws[WS_AL + mb + n];
      os += wg * ws[WS_AO + ((size_t)(bb * H_ + h) * NCH_ + n) * 64 + d];
    }
    oT[jj][bb] = os / ls;
  }
  __syncthreads();
  float a0 = 0.f, a1 = 0.f, a2 = 0.f, a3 = 0.f;
  #pragma unroll
  for (int i = 0; i < 16; ++i) {
    float w_ = wv[i];
    float4 o4 = *(float4*)&oT[i][0];
    a0 += w_ * o4.x; a1 += w_ * o4.y; a2 += w_ * o4.z; a3 += w_ * o4.w;
  }
  atomicAdd(ws + WS_HC + 0 * HID_ + col, MUP_ * a0);
  atomicAdd(ws + WS_HC + 1 * HID_ + col, MUP_ * a1);
  atomicAdd(ws + WS_HC + 2 * HID_ + col, MUP_ * a2);
  atomicAdd(ws + WS_HC + 3 * HID_ + col, MUP_ * a3);
}

// ================= K4: gate/up GEMV (RMS prologue on HC=h2) ==================
// grid 352 = 11 cb x 32 kc (32 rows each)
__global__ void __launch_bounds__(256)
k4_gateup(const float* __restrict__ Wg, const float* __restrict__ Wu,
          const float* __restrict__ n2, float* __restrict__ ws, int l) {
  int cb = blockIdx.x % 11, kc = blockIdx.x / 11;
  int t = threadIdx.x;
  int col = cb * 256 + t;
  const float* wgp = Wg + ((size_t)l * HID_ + kc * 32) * FF_ + col;
  const float* wup = Wu + ((size_t)l * HID_ + kc * 32) * FF_ + col;
  float gv[32], uv[32];
  #pragma unroll
  for (int i = 0; i < 32; ++i) { gv[i] = wgp[(size_t)i * FF_]; uv[i] = wup[(size_t)i * FF_]; }

  const float* hsrc = ws + WS_HC;
  __shared__ float red[16];
  __shared__ __align__(16) float xs[4][32];
  float rs[4];
  rms_of(hsrc, red, rs);
  if (t < 128) {
    int b = t >> 5, i = t & 31;
    int gc = kc * 32 + i;
    xs[b][i] = hsrc[b * HID_ + gc] * rs[b] * n2[l * HID_ + gc];
  }
  __syncthreads();
  float g0 = 0.f, g1 = 0.f, g2 = 0.f, g3 = 0.f;
  float u0 = 0.f, u1 = 0.f, u2 = 0.f, u3 = 0.f;
  #pragma unroll
  for (int i = 0; i < 32; ++i) {
    float g = gv[i], u = uv[i];
    float x0 = xs[0][i], x1 = xs[1][i], x2 = xs[2][i], x3 = xs[3][i];
    g0 += g * x0; g1 += g * x1; g2 += g * x2; g3 += g * x3;
    u0 += u * x0; u1 += u * x1; u2 += u * x2; u3 += u * x3;
  }
  ws[WS_GP + ((size_t)kc * 4 + 0) * FF_ + col] = g0;
  ws[WS_GP + ((size_t)kc * 4 + 1) * FF_ + col] = g1;
  ws[WS_GP + ((size_t)kc * 4 + 2) * FF_ + col] = g2;
  ws[WS_GP + ((size_t)kc * 4 + 3) * FF_ + col] = g3;
  ws[WS_UP + ((size_t)kc * 4 + 0) * FF_ + col] = u0;
  ws[WS_UP + ((size_t)kc * 4 + 1) * FF_ + col] = u1;
  ws[WS_UP + ((size_t)kc * 4 + 2) * FF_ + col] = u2;
  ws[WS_UP + ((size_t)kc * 4 + 3) * FF_ + col] = u3;
}

// ================= K5: down GEMV (silu-combine), atomicAdd into HC ===========
// grid 352 = 4 cb x 88 kc (32 rows each)
__global__ void __launch_bounds__(256)
k5_down(const float* __restrict__ Wd, float* __restrict__ ws, int l) {
  int cb = blockIdx.x & 3, kc = blockIdx.x >> 2;   // kc<88
  int t = threadIdx.x;
  int col = cb * 256 + t;
  const float* wp = Wd + ((size_t)l * FF_ + kc * 32) * HID_ + col;
  float wv[32];
  #pragma unroll
  for (int i = 0; i < 32; ++i) wv[i] = wp[(size_t)i * HID_];    // in flight

  __shared__ __align__(16) float mT[32][4];
  if (t < 128) {
    int jj = t >> 2, bb = t & 3;       // 128 items = 32 rows x 4 batches
    int f = kc * 32 + jj;
    float g = 0.f, u = 0.f;
    #pragma unroll
    for (int k2 = 0; k2 < 32; ++k2) {
      g += ws[WS_GP + ((size_t)k2 * 4 + bb) * FF_ + f];
      u += ws[WS_UP + ((size_t)k2 * 4 + bb) * FF_ + f];
    }
    float sig = 1.f / (1.f + expf(-g));
    mT[jj][bb] = g * sig * u;
  }
  __syncthreads();
  float a0 = 0.f, a1 = 0.f, a2 = 0.f, a3 = 0.f;
  #pragma unroll
  for (int i = 0; i < 32; ++i) {
    float w_ = wv[i];
    float4 m4 = *(float4*)&mT[i][0];
    a0 += w_ * m4.x; a1 += w_ * m4.y; a2 += w_ * m4.z; a3 += w_ * m4.w;
  }
  atomicAdd(ws + WS_HC + 0 * HID_ + col, MUP_ * a0);
  atomicAdd(ws + WS_HC + 1 * HID_ + col, MUP_ * a1);
  atomicAdd(ws + WS_HC + 2 * HID_ + col, MUP_ * a2);
  atomicAdd(ws + WS_HC + 3 * HID_ + col, MUP_ * a3);
}

// ================= K6: final RMS(HC)*fw -> out, plus pos+1 ===================
__global__ void __launch_bounds__(256)
k6_final(const float* __restrict__ fw, const int* __restrict__ posp,
         float* __restrict__ ws, float* __restrict__ out) {
  int b = blockIdx.x, t = threadIdx.x;
  __shared__ float red[4];
  float hv[4];
  float part = 0.f;
  for (int j = 0; j < 4; ++j) {
    float v = ws[WS_HC + b * HID_ + t + j * 256];
    hv[j] = v; part += v * v;
  }
  part = wave_sum(part);
  if ((t & 63) == 0) red[t >> 6] = part;
  __syncthreads();
  float rs = rsqrtf((red[0] + red[1] + red[2] + red[3]) * (1.0f / HID_) + EPS_);
  for (int j = 0; j < 4; ++j) {
    int c2 = t + j * 256;
    out[OUT_H + b * HID_ + c2] = hv[j] * rs * fw[c2];
  }
  if (b == 0 && t == 0) out[OUT_POS] = (float)(read_pos_dev(posp) + 1);
}

extern "C" void kernel_launch(void* const* d_in, const int* in_sizes, int n_in,
                              void* d_out, int out_size, void* d_ws, size_t ws_size,
                              hipStream_t stream) {
  const float* x   = (const float*)d_in[0];
  const float* kcp = (const float*)d_in[1];
  const float* vcp = (const float*)d_in[2];
  const float* Wq  = (const float*)d_in[3];
  const float* Wk  = (const float*)d_in[4];
  const float* Wv  = (const float*)d_in[5];
  const float* Wo  = (const float*)d_in[6];
  const float* Wg  = (const float*)d_in[7];
  const float* Wu  = (const float*)d_in[8];
  const float* Wd  = (const float*)d_in[9];
  const float* n1  = (const float*)d_in[10];
  const float* n2  = (const float*)d_in[11];
  const float* fw  = (const float*)d_in[12];
  const int*   pos = (const int*)d_in[13];
  float* ws  = (float*)d_ws;
  float* out = (float*)d_out;

  for (int l = 0; l < L_; ++l) {
    k1_qkv   <<< 256, 256, 0, stream>>>(Wq, Wk, Wv, n1, x, ws, l);
    k2_attn  <<<1024, 256, 0, stream>>>(kcp, vcp, pos, ws, out, l);
    k3_oproj <<< 256, 256, 0, stream>>>(Wo, ws, l);
    k4_gateup<<< 352, 256, 0, stream>>>(Wg, Wu, n2, ws, l);
    k5_down  <<< 352, 256, 0, stream>>>(Wd, ws, l);
  }
  k6_final<<<4, 256, 0, stream>>>(fw, pos, ws, out);
}

// Round 11
// 320.700 us; speedup vs baseline: 1.0114x; 1.0114x over previous
//
#include <hip/hip_runtime.h>

// MiniCPM-style decode step: L=8 B=4 H=16 HKV=8 D=64 S=2048 HID=1024 FF=2816
#define L_   8
#define B_   4
#define H_   16
#define HKV_ 8
#define D_   64
#define S_   2048
#define HID_ 1024
#define FF_  2816
#define EPS_ 1e-5f
#define MUP_ 0.49497474683058327f   // 1.4/sqrt(8)
#define SCALE_ 0.125f               // 1/sqrt(64)
#define NCH_ 32                     // attention chunks of 64 positions

// d_out is FLOAT32: [h 4096 | k_upd 16384 | v_upd 16384 | pos+1]
#define OUT_H   0
#define OUT_K   4096
#define OUT_V   (4096 + 16384)
#define OUT_POS (4096 + 16384 + 16384)

// ---------------- workspace layout (floats); partials [kc][b][col] ----------------
enum {
  WS_HC  = 0,                        // 4096   live hidden state (atomics target)
  WS_QP  = 4096,                     // 32*4*2048 = 262144
  WS_AM  = WS_QP + 262144,           // 2048   [b][kv][2][32]
  WS_AL  = WS_AM + 2048,             // 2048
  WS_AO  = WS_AL + 2048,             // 4*16*32*64 = 131072
  WS_GP  = WS_AO + 131072,           // 32*4*2816 = 360448
  WS_UP  = WS_GP + 360448,           // 360448
  WS_END = WS_UP + 360448            // ~4.5 MB
};

__device__ __forceinline__ int read_pos_dev(const int* p) {
  int v = p[0];
  if (v >= 0 && v < S_) return v;
  float f = __int_as_float(v);
  if (f >= 0.0f && f <= (float)(S_ - 1)) return (int)(f + 0.5f);
  return 1500;
}

__device__ __forceinline__ float wave_sum(float v) {
  for (int m = 1; m < 64; m <<= 1) v += __shfl_xor(v, m);
  return v;
}
__device__ __forceinline__ float wave_max(float v) {
  for (int m = 1; m < 64; m <<= 1) v = fmaxf(v, __shfl_xor(v, m));
  return v;
}
__device__ __forceinline__ void keepf(float v) { asm volatile("" :: "v"(v)); }

// shared RMS prologue: read 4x1024 h, per-batch rsqrt(mean sq)
__device__ __forceinline__ void rms_of(const float* hsrc, float* red, float* rs) {
  int t = threadIdx.x;
  float part[4] = {0.f, 0.f, 0.f, 0.f};
  #pragma unroll
  for (int j = 0; j < 4; ++j) {
    int c2 = t + j * 256;
    #pragma unroll
    for (int b = 0; b < 4; ++b) {
      float v = hsrc[b * HID_ + c2];
      part[b] += v * v;
    }
  }
  int w = t >> 6;
  #pragma unroll
  for (int b = 0; b < 4; ++b) {
    float s = wave_sum(part[b]);
    if ((t & 63) == 0) red[w * 4 + b] = s;
  }
  __syncthreads();
  #pragma unroll
  for (int b = 0; b < 4; ++b)
    rs[b] = rsqrtf((red[b] + red[4 + b] + red[8 + b] + red[12 + b]) * (1.0f / HID_) + EPS_);
}

// ================= K1: QKV GEMV + prefetch this layer's KV for k2 ============
// grid 256 = 8 cb x 32 kc (32 rows each)
__global__ void __launch_bounds__(256)
k1_qkv(const float* __restrict__ Wq, const float* __restrict__ Wk,
       const float* __restrict__ Wv, const float* __restrict__ n1,
       const float* __restrict__ x, const float* __restrict__ kcache,
       const float* __restrict__ vcache, const int* __restrict__ posp,
       float* __restrict__ ws, int l) {
  int cb = blockIdx.x & 7, kc = blockIdx.x >> 3;
  int t = threadIdx.x;
  int col = cb * 256 + t;
  const float* W; int wcol, stride;
  if (col < 1024)      { W = Wq + (size_t)l * HID_ * 1024; wcol = col;        stride = 1024; }
  else if (col < 1536) { W = Wk + (size_t)l * HID_ * 512;  wcol = col - 1024; stride = 512;  }
  else                 { W = Wv + (size_t)l * HID_ * 512;  wcol = col - 1536; stride = 512;  }
  const float* wp = W + (size_t)(kc * 32) * stride + wcol;
  float wv[32];
  #pragma unroll
  for (int i = 0; i < 32; ++i) wv[i] = wp[(size_t)i * stride];   // own, oldest

  const float* hsrc = (l == 0) ? x : (ws + WS_HC);
  __shared__ float red[16];
  __shared__ __align__(16) float xs[4][32];
  float rs[4];
  rms_of(hsrc, red, rs);
  if (l == 0 && blockIdx.x < 4) {        // seed HC = x
    for (int j = 0; j < 4; ++j) {
      int c2 = t + j * 256;
      ws[WS_HC + blockIdx.x * HID_ + c2] = x[blockIdx.x * HID_ + c2];
    }
  }
  if (t < 128) {
    int b = t >> 5, i = t & 31;
    int gc = kc * 32 + i;
    xs[b][i] = hsrc[b * HID_ + gc] * rs[b] * n1[l * HID_ + gc];
  }

  // ---- prefetch KV for k2 blocks {bid + m*256} (issued after all own loads) ----
  int pos = read_pos_dev(posp);
  float pf[8];
  {
    int row = t >> 2, off = (t & 3) * 16;    // one 64B line per thread per tensor
    #pragma unroll
    for (int m = 0; m < 4; ++m) {
      int j = blockIdx.x + m * 256;          // k2 block id (same XCD: j%8==bid%8)
      int bh2 = j >> 5, ns2 = j & 31;
      int s02 = ns2 * 64;
      bool act = (s02 <= pos);
      size_t base = (((size_t)l * B_ + (bh2 >> 3)) * HKV_ + (bh2 & 7)) * S_ * 64
                  + (size_t)(s02 + row) * 64 + off;
      pf[2 * m + 0] = act ? kcache[base] : 0.f;
      pf[2 * m + 1] = act ? vcache[base] : 0.f;
    }
  }
  __syncthreads();
  float a0 = 0.f, a1 = 0.f, a2 = 0.f, a3 = 0.f;
  #pragma unroll
  for (int i = 0; i < 32; ++i) {
    float w_ = wv[i];
    a0 += w_ * xs[0][i]; a1 += w_ * xs[1][i];
    a2 += w_ * xs[2][i]; a3 += w_ * xs[3][i];
  }
  ws[WS_QP + ((size_t)kc * 4 + 0) * 2048 + col] = a0;
  ws[WS_QP + ((size_t)kc * 4 + 1) * 2048 + col] = a1;
  ws[WS_QP + ((size_t)kc * 4 + 2) * 2048 + col] = a2;
  ws[WS_QP + ((size_t)kc * 4 + 3) * 2048 + col] = a3;
  #pragma unroll
  for (int m = 0; m < 8; ++m) keepf(pf[m]);
}

// ================= K2: qkv-combine + rope + kv-out + flash chunk; prefetch Wo ==
// grid 1024 = (b,kv) x 32 chunks of 64 positions
__global__ void __launch_bounds__(256)
k2_attn(const float* __restrict__ kcache, const float* __restrict__ vcache,
        const int* __restrict__ posp, const float* __restrict__ Wo,
        float* __restrict__ ws, float* __restrict__ out, int l) {
  int bh = blockIdx.x >> 5, ns = blockIdx.x & 31;
  int b = bh >> 3, kv = bh & 7;
  int t = threadIdx.x;
  int w = t >> 6, lane = t & 63, r = lane >> 4, c = lane & 15;
  int pos = read_pos_dev(posp);
  int s0 = ns * 64;

  // prefetch Wo region of k3 block bid (blocks <256; identity, XCD-aligned)
  float pfo = 0.f;
  if (blockIdx.x < 256) {
    int cb3 = blockIdx.x & 3, kc3 = blockIdx.x >> 2;
    int r3 = t >> 4, c3 = (t & 15) * 16;
    pfo = Wo[((size_t)l * HID_ + kc3 * 16 + r3) * HID_ + cb3 * 256 + c3];
  }

  if (s0 > pos) {                      // fully-masked chunk: sentinels only
    if (t == 0) {
      int base = ((b * HKV_ + kv) * 2) * NCH_ + ns;
      ws[WS_AM + base] = -1e30f;       ws[WS_AM + base + NCH_] = -1e30f;
      ws[WS_AL + base] = 0.f;          ws[WS_AL + base + NCH_] = 0.f;
    }
    keepf(pfo);
    return;
  }
  __shared__ __align__(16) float Kst[64 * 68];
  __shared__ __align__(16) float Vst[64 * 68];
  __shared__ __align__(16) float qL[2][64];
  __shared__ __align__(16) float knL[64], vnL[64];
  __shared__ float rawL[256], sc0[64], sc1[64], red[8];
  __shared__ __align__(16) float oacc[2][4][64];

  const float* Kb = kcache + (((size_t)l * B_ + b) * HKV_ + kv) * S_ * 64;
  const float* Vb = vcache + (((size_t)l * B_ + b) * HKV_ + kv) * S_ * 64;

  {
    const float4* Ksrc = (const float4*)(Kb + (size_t)s0 * 64);
    const float4* Vsrc = (const float4*)(Vb + (size_t)s0 * 64);
    #pragma unroll
    for (int i = 0; i < 4; ++i) {
      int f4 = t + i * 256;
      int row = f4 >> 4, c4 = f4 & 15;
      float4 kk = Ksrc[f4];
      float4 vv = Vsrc[f4];
      *(float4*)&Kst[row * 68 + 4 * c4] = kk;
      *(float4*)&Vst[row * 68 + 4 * c4] = vv;
    }
  }

  int cg;
  if (t < 128)      cg = (kv * 2 + (t >> 6)) * 64 + (t & 63);
  else if (t < 192) cg = 1024 + kv * 64 + (t & 63);
  else              cg = 1536 + kv * 64 + (t & 63);
  float s = 0.f;
  #pragma unroll
  for (int q = 0; q < 32; ++q) s += ws[WS_QP + ((size_t)q * 4 + b) * 2048 + cg];
  rawL[t] = s;
  __syncthreads();
  {
    int dd = t & 63;
    if (t < 192) {
      int idx = dd & 31;
      float inv = expf(-(float)idx * (1.0f / 32.0f) * 9.210340371976184f);
      float ang = (float)pos * inv;
      float sn, cs; __sincosf(ang, &sn, &cs);
      float partner = rawL[t ^ 32];
      float rot = (dd < 32) ? -partner : partner;
      float v = rawL[t] * cs + rot * sn;
      if (t < 128) qL[t >> 6][dd] = v;
      else {
        knL[dd] = v;
        if (ns == 0) out[OUT_K + (((size_t)l * B_ + b) * HKV_ + kv) * 64 + dd] = v;
      }
    } else {
      vnL[dd] = rawL[t];
      if (ns == 0) out[OUT_V + (((size_t)l * B_ + b) * HKV_ + kv) * 64 + dd] = rawL[t];
    }
  }
  __syncthreads();
  if (pos >= s0 && pos < s0 + 64) {
    int row = pos - s0;
    if (t < 64)                Kst[row * 68 + t] = knL[t];
    else if (t < 128)          Vst[row * 68 + (t - 64)] = vnL[t - 64];
  }
  __syncthreads();

  float4 q0 = *(float4*)&qL[0][4 * c];
  float4 q1 = *(float4*)&qL[1][4 * c];
  #pragma unroll
  for (int it = 0; it < 4; ++it) {
    int row = it * 16 + w * 4 + r;
    int sp = s0 + row;
    float4 k4 = *(float4*)&Kst[row * 68 + 4 * c];
    float d0 = k4.x * q0.x + k4.y * q0.y + k4.z * q0.z + k4.w * q0.w;
    float d1 = k4.x * q1.x + k4.y * q1.y + k4.z * q1.z + k4.w * q1.w;
    #pragma unroll
    for (int m = 1; m <= 8; m <<= 1) { d0 += __shfl_xor(d0, m); d1 += __shfl_xor(d1, m); }
    if (c == 0) {
      bool valid = (sp <= pos);
      sc0[row] = valid ? d0 * SCALE_ : -1e30f;
      sc1[row] = valid ? d1 * SCALE_ : -1e30f;
    }
  }
  __syncthreads();
  float v0 = (t < 64) ? sc0[t] : -1e30f;
  float v1 = (t < 64) ? sc1[t] : -1e30f;
  float m0 = wave_max(v0), m1 = wave_max(v1);
  if (lane == 0) { red[w] = m0; red[4 + w] = m1; }
  __syncthreads();
  m0 = fmaxf(fmaxf(red[0], red[1]), fmaxf(red[2], red[3]));
  m1 = fmaxf(fmaxf(red[4], red[5]), fmaxf(red[6], red[7]));
  float e0 = (t < 64) ? expf(v0 - m0) : 0.f;
  float e1 = (t < 64) ? expf(v1 - m1) : 0.f;
  __syncthreads();
  if (t < 64) { sc0[t] = e0; sc1[t] = e1; }
  float se0 = wave_sum(e0), se1 = wave_sum(e1);
  if (lane == 0) { red[w] = se0; red[4 + w] = se1; }
  __syncthreads();
  if (t == 0) {
    int base = ((b * HKV_ + kv) * 2) * NCH_ + ns;
    ws[WS_AM + base] = m0;          ws[WS_AM + base + NCH_] = m1;
    ws[WS_AL + base] = red[0] + red[1] + red[2] + red[3];
    ws[WS_AL + base + NCH_] = red[4] + red[5] + red[6] + red[7];
  }
  float4 a0 = make_float4(0.f, 0.f, 0.f, 0.f);
  float4 a1 = make_float4(0.f, 0.f, 0.f, 0.f);
  #pragma unroll
  for (int it = 0; it < 4; ++it) {
    int row = it * 16 + w * 4 + r;
    float4 v4 = *(float4*)&Vst[row * 68 + 4 * c];
    float p0 = sc0[row], p1 = sc1[row];
    a0.x += p0 * v4.x; a0.y += p0 * v4.y; a0.z += p0 * v4.z; a0.w += p0 * v4.w;
    a1.x += p1 * v4.x; a1.y += p1 * v4.y; a1.z += p1 * v4.z; a1.w += p1 * v4.w;
  }
  #pragma unroll
  for (int m = 16; m <= 32; m <<= 1) {
    a0.x += __shfl_xor(a0.x, m); a0.y += __shfl_xor(a0.y, m);
    a0.z += __shfl_xor(a0.z, m); a0.w += __shfl_xor(a0.w, m);
    a1.x += __shfl_xor(a1.x, m); a1.y += __shfl_xor(a1.y, m);
    a1.z += __shfl_xor(a1.z, m); a1.w += __shfl_xor(a1.w, m);
  }
  if (r == 0) {
    *(float4*)&oacc[0][w][4 * c] = a0;
    *(float4*)&oacc[1][w][4 * c] = a1;
  }
  __syncthreads();
  if (t < 64) {
    float r0 = oacc[0][0][t] + oacc[0][1][t] + oacc[0][2][t] + oacc[0][3][t];
    float r1 = oacc[1][0][t] + oacc[1][1][t] + oacc[1][2][t] + oacc[1][3][t];
    int h0 = kv * 2;
    ws[WS_AO + ((size_t)(b * H_ + h0)     * NCH_ + ns) * 64 + t] = r0;
    ws[WS_AO + ((size_t)(b * H_ + h0 + 1) * NCH_ + ns) * 64 + t] = r1;
  }
  keepf(pfo);
}

// ================= K3: o-proj GEMV + atomic residual; prefetch Wg/Wu =========
// grid 256 = 4 cb x 64 kc (16 rows each)
__global__ void __launch_bounds__(256)
k3_oproj(const float* __restrict__ Wo, const float* __restrict__ Wg,
         const float* __restrict__ Wu, float* __restrict__ ws, int l) {
  int cb = blockIdx.x & 3, kc = blockIdx.x >> 2;
  int t = threadIdx.x;
  int col = cb * 256 + t;
  const float* wp = Wo + ((size_t)l * HID_ + kc * 16) * HID_ + col;
  float wv[16];
  #pragma unroll
  for (int i = 0; i < 16; ++i) wv[i] = wp[(size_t)i * HID_];

  __shared__ __align__(16) float oT[16][4];
  if (t < 64) {
    int jj = t >> 2, bb = t & 3;
    int dim = kc * 16 + jj, h = dim >> 6, d = dim & 63;
    int mb = ((bb * HKV_ + (h >> 1)) * 2 + (h & 1)) * NCH_;
    float mx = -1e30f;
    #pragma unroll
    for (int n = 0; n < NCH_; ++n) mx = fmaxf(mx, ws[WS_AM + mb + n]);
    float ls = 0.f, os = 0.f;
    #pragma unroll
    for (int n = 0; n < NCH_; ++n) {
      float wg = expf(ws[WS_AM + mb + n] - mx);
      ls += wg * ws[WS_AL + mb + n];
      os += wg * ws[WS_AO + ((size_t)(bb * H_ + h) * NCH_ + n) * 64 + d];
    }
    oT[jj][bb] = os / ls;
  }

  // ---- prefetch Wg/Wu regions of k4 blocks bid (+256 if bid<96) ----
  float pf[8];
  {
    #pragma unroll
    for (int rg = 0; rg < 2; ++rg) {
      int j = blockIdx.x + rg * 256;
      bool act = (j < 352);
      int jj2 = act ? j : 0;
      int cb4 = jj2 % 11, kc4 = jj2 / 11;
      #pragma unroll
      for (int q = 0; q < 2; ++q) {
        int m = t + q * 256;                // 0..511 lines of the 32x256 region
        int r4 = m >> 4, c4 = (m & 15) * 16;
        size_t o4 = ((size_t)l * HID_ + kc4 * 32 + r4) * FF_ + cb4 * 256 + c4;
        pf[rg * 4 + q * 2 + 0] = act ? Wg[o4] : 0.f;
        pf[rg * 4 + q * 2 + 1] = act ? Wu[o4] : 0.f;
      }
    }
  }
  __syncthreads();
  float a0 = 0.f, a1 = 0.f, a2 = 0.f, a3 = 0.f;
  #pragma unroll
  for (int i = 0; i < 16; ++i) {
    float w_ = wv[i];
    float4 o4 = *(float4*)&oT[i][0];
    a0 += w_ * o4.x; a1 += w_ * o4.y; a2 += w_ * o4.z; a3 += w_ * o4.w;
  }
  atomicAdd(ws + WS_HC + 0 * HID_ + col, MUP_ * a0);
  atomicAdd(ws + WS_HC + 1 * HID_ + col, MUP_ * a1);
  atomicAdd(ws + WS_HC + 2 * HID_ + col, MUP_ * a2);
  atomicAdd(ws + WS_HC + 3 * HID_ + col, MUP_ * a3);
  #pragma unroll
  for (int m = 0; m < 8; ++m) keepf(pf[m]);
}

// ================= K4: gate/up GEMV (RMS on HC); prefetch Wd =================
// grid 352 = 11 cb x 32 kc (32 rows each)
__global__ void __launch_bounds__(256)
k4_gateup(const float* __restrict__ Wg, const float* __restrict__ Wu,
          const float* __restrict__ Wd, const float* __restrict__ n2,
          float* __restrict__ ws, int l) {
  int cb = blockIdx.x % 11, kc = blockIdx.x / 11;
  int t = threadIdx.x;
  int col = cb * 256 + t;
  const float* wgp = Wg + ((size_t)l * HID_ + kc * 32) * FF_ + col;
  const float* wup = Wu + ((size_t)l * HID_ + kc * 32) * FF_ + col;
  float gv[32], uv[32];
  #pragma unroll
  for (int i = 0; i < 32; ++i) { gv[i] = wgp[(size_t)i * FF_]; uv[i] = wup[(size_t)i * FF_]; }

  const float* hsrc = ws + WS_HC;
  __shared__ float red[16];
  __shared__ __align__(16) float xs[4][32];
  float rs[4];
  rms_of(hsrc, red, rs);
  if (t < 128) {
    int b = t >> 5, i = t & 31;
    int gc = kc * 32 + i;
    xs[b][i] = hsrc[b * HID_ + gc] * rs[b] * n2[l * HID_ + gc];
  }

  // ---- prefetch Wd region of k5 block bid (identity mapping) ----
  float pf[2];
  {
    int cb5 = blockIdx.x & 3, kc5 = blockIdx.x >> 2;   // k5 block bid
    #pragma unroll
    for (int q = 0; q < 2; ++q) {
      int m = t + q * 256;
      int r5 = m >> 4, c5 = (m & 15) * 16;
      pf[q] = Wd[((size_t)l * FF_ + kc5 * 32 + r5) * HID_ + cb5 * 256 + c5];
    }
  }
  __syncthreads();
  float g0 = 0.f, g1 = 0.f, g2 = 0.f, g3 = 0.f;
  float u0 = 0.f, u1 = 0.f, u2 = 0.f, u3 = 0.f;
  #pragma unroll
  for (int i = 0; i < 32; ++i) {
    float g = gv[i], u = uv[i];
    float x0 = xs[0][i], x1 = xs[1][i], x2 = xs[2][i], x3 = xs[3][i];
    g0 += g * x0; g1 += g * x1; g2 += g * x2; g3 += g * x3;
    u0 += u * x0; u1 += u * x1; u2 += u * x2; u3 += u * x3;
  }
  ws[WS_GP + ((size_t)kc * 4 + 0) * FF_ + col] = g0;
  ws[WS_GP + ((size_t)kc * 4 + 1) * FF_ + col] = g1;
  ws[WS_GP + ((size_t)kc * 4 + 2) * FF_ + col] = g2;
  ws[WS_GP + ((size_t)kc * 4 + 3) * FF_ + col] = g3;
  ws[WS_UP + ((size_t)kc * 4 + 0) * FF_ + col] = u0;
  ws[WS_UP + ((size_t)kc * 4 + 1) * FF_ + col] = u1;
  ws[WS_UP + ((size_t)kc * 4 + 2) * FF_ + col] = u2;
  ws[WS_UP + ((size_t)kc * 4 + 3) * FF_ + col] = u3;
  keepf(pf[0]); keepf(pf[1]);
}

// ================= K5: down GEMV + atomic residual; prefetch next QKV ========
// grid 352 = 4 cb x 88 kc (32 rows each)
__global__ void __launch_bounds__(256)
k5_down(const float* __restrict__ Wd, const float* __restrict__ Wq,
        const float* __restrict__ Wk, const float* __restrict__ Wv,
        float* __restrict__ ws, int l) {
  int cb = blockIdx.x & 3, kc = blockIdx.x >> 2;   // kc<88
  int t = threadIdx.x;
  int col = cb * 256 + t;
  const float* wp = Wd + ((size_t)l * FF_ + kc * 32) * HID_ + col;
  float wv[32];
  #pragma unroll
  for (int i = 0; i < 32; ++i) wv[i] = wp[(size_t)i * HID_];

  __shared__ __align__(16) float mT[32][4];
  if (t < 128) {
    int jj = t >> 2, bb = t & 3;
    int f = kc * 32 + jj;
    float g = 0.f, u = 0.f;
    #pragma unroll
    for (int k2 = 0; k2 < 32; ++k2) {
      g += ws[WS_GP + ((size_t)k2 * 4 + bb) * FF_ + f];
      u += ws[WS_UP + ((size_t)k2 * 4 + bb) * FF_ + f];
    }
    float sig = 1.f / (1.f + expf(-g));
    mT[jj][bb] = g * sig * u;
  }

  // ---- prefetch next-layer QKV region of k1 block bid (blocks <256) ----
  float pf[2] = {0.f, 0.f};
  if (l + 1 < L_ && blockIdx.x < 256) {
    int cb1 = blockIdx.x & 7, kc1 = blockIdx.x >> 3;
    #pragma unroll
    for (int q = 0; q < 2; ++q) {
      int m = t + q * 256;
      int r1 = m >> 4, c1 = (m & 15) * 16;
      int pcol = cb1 * 256 + c1;
      const float* W1; int wcol1, stride1;
      if (pcol < 1024)      { W1 = Wq + (size_t)(l + 1) * HID_ * 1024; wcol1 = pcol;        stride1 = 1024; }
      else if (pcol < 1536) { W1 = Wk + (size_t)(l + 1) * HID_ * 512;  wcol1 = pcol - 1024; stride1 = 512;  }
      else                  { W1 = Wv + (size_t)(l + 1) * HID_ * 512;  wcol1 = pcol - 1536; stride1 = 512;  }
      pf[q] = W1[(size_t)(kc1 * 32 + r1) * stride1 + wcol1];
    }
  }
  __syncthreads();
  float a0 = 0.f, a1 = 0.f, a2 = 0.f, a3 = 0.f;
  #pragma unroll
  for (int i = 0; i < 32; ++i) {
    float w_ = wv[i];
    float4 m4 = *(float4*)&mT[i][0];
    a0 += w_ * m4.x; a1 += w_ * m4.y; a2 += w_ * m4.z; a3 += w_ * m4.w;
  }
  atomicAdd(ws + WS_HC + 0 * HID_ + col, MUP_ * a0);
  atomicAdd(ws + WS_HC + 1 * HID_ + col, MUP_ * a1);
  atomicAdd(ws + WS_HC + 2 * HID_ + col, MUP_ * a2);
  atomicAdd(ws + WS_HC + 3 * HID_ + col, MUP_ * a3);
  keepf(pf[0]); keepf(pf[1]);
}

// ================= K6: final RMS(HC)*fw -> out, plus pos+1 ===================
__global__ void __launch_bounds__(256)
k6_final(const float* __restrict__ fw, const int* __restrict__ posp,
         float* __restrict__ ws, float* __restrict__ out) {
  int b = blockIdx.x, t = threadIdx.x;
  __shared__ float red[4];
  float hv[4];
  float part = 0.f;
  for (int j = 0; j < 4; ++j) {
    float v = ws[WS_HC + b * HID_ + t + j * 256];
    hv[j] = v; part += v * v;
  }
  part = wave_sum(part);
  if ((t & 63) == 0) red[t >> 6] = part;
  __syncthreads();
  float rs = rsqrtf((red[0] + red[1] + red[2] + red[3]) * (1.0f / HID_) + EPS_);
  for (int j = 0; j < 4; ++j) {
    int c2 = t + j * 256;
    out[OUT_H + b * HID_ + c2] = hv[j] * rs * fw[c2];
  }
  if (b == 0 && t == 0) out[OUT_POS] = (float)(read_pos_dev(posp) + 1);
}

extern "C" void kernel_launch(void* const* d_in, const int* in_sizes, int n_in,
                              void* d_out, int out_size, void* d_ws, size_t ws_size,
                              hipStream_t stream) {
  const float* x   = (const float*)d_in[0];
  const float* kcp = (const float*)d_in[1];
  const float* vcp = (const float*)d_in[2];
  const float* Wq  = (const float*)d_in[3];
  const float* Wk  = (const float*)d_in[4];
  const float* Wv  = (const float*)d_in[5];
  const float* Wo  = (const float*)d_in[6];
  const float* Wg  = (const float*)d_in[7];
  const float* Wu  = (const float*)d_in[8];
  const float* Wd  = (const float*)d_in[9];
  const float* n1  = (const float*)d_in[10];
  const float* n2  = (const float*)d_in[11];
  const float* fw  = (const float*)d_in[12];
  const int*   pos = (const int*)d_in[13];
  float* ws  = (float*)d_ws;
  float* out = (float*)d_out;

  for (int l = 0; l < L_; ++l) {
    k1_qkv   <<< 256, 256, 0, stream>>>(Wq, Wk, Wv, n1, x, kcp, vcp, pos, ws, l);
    k2_attn  <<<1024, 256, 0, stream>>>(kcp, vcp, pos, Wo, ws, out, l);
    k3_oproj <<< 256, 256, 0, stream>>>(Wo, Wg, Wu, ws, l);
    k4_gateup<<< 352, 256, 0, stream>>>(Wg, Wu, Wd, n2, ws, l);
    k5_down  <<< 352, 256, 0, stream>>>(Wd, Wq, Wk, Wv, ws, l);
  }
  k6_final<<<4, 256, 0, stream>>>(fw, pos, ws, out);
}